// Round 2
// baseline (322.884 us; speedup 1.0000x reference)
//
#include <hip/hip_runtime.h>
#include <hip/hip_bf16.h>
#include <stdint.h>

#define BATCH 4
#define SEQ   4096
#define EMB   1024
#define HD    64

typedef __bf16 bf16x8 __attribute__((ext_vector_type(8)));
typedef float  f32x4  __attribute__((ext_vector_type(4)));
typedef unsigned short u16;

union ABFrag { u16 s[8]; bf16x8 v; };

__device__ __forceinline__ u16 f2bf_rne(float f) {
    union { float f; uint32_t u; } cv; cv.f = f;
    uint32_t u = cv.u;
    return (u16)((u + 0x7fffu + ((u >> 16) & 1u)) >> 16);
}
__device__ __forceinline__ float bf2f(u16 h) {
    union { uint32_t u; float f; } cv; cv.u = ((uint32_t)h) << 16;
    return cv.f;
}

// ---------------------------------------------------------------------------
// Kernel 0: W (1024,64) fp32 x3 -> Wt bf16 [3][64][1024]  (transposed)
// ---------------------------------------------------------------------------
__global__ __launch_bounds__(256) void wt_kernel(
        const float* __restrict__ Wq, const float* __restrict__ Wk,
        const float* __restrict__ Wv, u16* __restrict__ Wt) {
    int idx = blockIdx.x * 256 + threadIdx.x;   // 0 .. 3*65536-1
    int i = idx >> 16;
    int r = idx & 65535;
    int n = r >> 10;      // 0..63  (head dim)
    int k = r & 1023;     // 0..1023 (embed dim)
    const float* W = (i == 0) ? Wq : (i == 1) ? Wk : Wv;
    Wt[idx] = f2bf_rne(W[k * HD + n]);
}

// ---------------------------------------------------------------------------
// Kernel 1: QKV projection, one weight matrix per block (3x blocks => 3x
// occupancy; x reads 3x but L3-absorbed). Block = 4 waves x 16 rows.
// ---------------------------------------------------------------------------
__global__ __launch_bounds__(256) void qkv_kernel(
        const float* __restrict__ x, const u16* __restrict__ Wt,
        u16* __restrict__ Qw, u16* __restrict__ Kw, u16* __restrict__ Vt) {
    const int w3     = blockIdx.x % 3;       // which weight
    const int rowblk = blockIdx.x / 3;       // 0..255
    const int wave = threadIdx.x >> 6;
    const int lane = threadIdx.x & 63;
    const int m16  = lane & 15;
    const int quad = lane >> 4;
    const int row  = rowblk * 64 + wave * 16 + m16;   // 0..16383

    f32x4 acc[4];
#pragma unroll
    for (int nt = 0; nt < 4; ++nt) acc[nt] = (f32x4){0.f, 0.f, 0.f, 0.f};

    const float* xrow = x + (size_t)row * EMB + (quad << 3);
    const u16*   wtl  = Wt + (w3 << 16) + (m16 << 10) + (quad << 3);

    for (int ks = 0; ks < 32; ++ks) {
        float4 a0 = *(const float4*)(xrow + (ks << 5));
        float4 a1 = *(const float4*)(xrow + (ks << 5) + 4);
        ABFrag af;
        af.s[0] = f2bf_rne(a0.x); af.s[1] = f2bf_rne(a0.y);
        af.s[2] = f2bf_rne(a0.z); af.s[3] = f2bf_rne(a0.w);
        af.s[4] = f2bf_rne(a1.x); af.s[5] = f2bf_rne(a1.y);
        af.s[6] = f2bf_rne(a1.z); af.s[7] = f2bf_rne(a1.w);
#pragma unroll
        for (int nt = 0; nt < 4; ++nt) {
            bf16x8 bf = *(const bf16x8*)(wtl + (nt << 14) + (ks << 5));
            acc[nt] = __builtin_amdgcn_mfma_f32_16x16x32_bf16(af.v, bf, acc[nt], 0, 0, 0);
        }
    }

    // C layout: lane holds rows quad*4+reg, col = m16 + 16*nt
    const int rowbase = rowblk * 64 + wave * 16 + (quad << 2);
    const int bidx = rowbase >> 12;
    const int t0   = rowbase & 4095;
    if (w3 == 0) {
#pragma unroll
        for (int nt = 0; nt < 4; ++nt) {
            const int col = m16 + (nt << 4);
#pragma unroll
            for (int reg = 0; reg < 4; ++reg)
                Qw[(size_t)(rowbase + reg) * HD + col] = f2bf_rne(acc[nt][reg] * 0.03125f);
        }
    } else if (w3 == 1) {
#pragma unroll
        for (int nt = 0; nt < 4; ++nt) {
            const int col = m16 + (nt << 4);
#pragma unroll
            for (int reg = 0; reg < 4; ++reg)
                Kw[(size_t)(rowbase + reg) * HD + col] = f2bf_rne(acc[nt][reg]);
        }
    } else {
#pragma unroll
        for (int nt = 0; nt < 4; ++nt) {
            const int col = m16 + (nt << 4);
            ushort4 vv;
            vv.x = f2bf_rne(acc[nt][0]); vv.y = f2bf_rne(acc[nt][1]);
            vv.z = f2bf_rne(acc[nt][2]); vv.w = f2bf_rne(acc[nt][3]);
            *(ushort4*)(Vt + (size_t)((bidx << 6) + col) * SEQ + t0) = vv;
        }
    }
}

// ---------------------------------------------------------------------------
// Kernel 2: split-K causal flash attention (partial pass).
// Grid = b(4) x qtile(64) x chunk(4); chunk c covers kv tiles [16c,16c+16)∩[0,qt].
// Block = 4 waves = 64 Q rows. Writes unnormalized O (bf16) + m,l (fp32).
// ---------------------------------------------------------------------------
__global__ __launch_bounds__(256) void attn_part_kernel(
        const u16* __restrict__ Qw, const u16* __restrict__ Kw,
        const u16* __restrict__ Vt, u16* __restrict__ Opart,
        float* __restrict__ Mp, float* __restrict__ Lp) {
    __shared__ u16 ldsP[4][16 * 72];

    const int pid  = blockIdx.x;
    const int b    = pid >> 8;
    const int qt   = (pid >> 2) & 63;
    const int c    = pid & 3;
    const int wave = threadIdx.x >> 6;
    const int lane = threadIdx.x & 63;
    const int m16  = lane & 15;
    const int quad = lane >> 4;

    const int j0   = c << 4;
    const int jend = min(j0 + 16, qt + 1);

    const int qrow = (qt << 6) + (wave << 4) + m16;
    const u16* qbase = Qw + ((size_t)(b * SEQ + qrow) << 6);
    const bf16x8 qf0 = *(const bf16x8*)(qbase + (quad << 3));
    const bf16x8 qf1 = *(const bf16x8*)(qbase + 32 + (quad << 3));

    f32x4 acc_o[4];
#pragma unroll
    for (int nt = 0; nt < 4; ++nt) acc_o[nt] = (f32x4){0.f, 0.f, 0.f, 0.f};
    float m_i[4] = {-3.0e38f, -3.0e38f, -3.0e38f, -3.0e38f};
    float l_i[4] = {0.f, 0.f, 0.f, 0.f};

    u16* ldsW = &ldsP[wave][0];

    for (int jt = j0; jt < jend; ++jt) {
        f32x4 s[4];
#pragma unroll
        for (int nt = 0; nt < 4; ++nt) s[nt] = (f32x4){0.f, 0.f, 0.f, 0.f};
        const u16* kbase = Kw + ((size_t)(b * SEQ + (jt << 6) + m16) << 6) + (quad << 3);
#pragma unroll
        for (int nt = 0; nt < 4; ++nt) {
            bf16x8 k0 = *(const bf16x8*)(kbase + (nt << 10));
            bf16x8 k1 = *(const bf16x8*)(kbase + (nt << 10) + 32);
            s[nt] = __builtin_amdgcn_mfma_f32_16x16x32_bf16(qf0, k0, s[nt], 0, 0, 0);
            s[nt] = __builtin_amdgcn_mfma_f32_16x16x32_bf16(qf1, k1, s[nt], 0, 0, 0);
        }

        if (jt == qt) {   // causal mask on diagonal tile
            const int rowin = (wave << 4) + (quad << 2);
#pragma unroll
            for (int nt = 0; nt < 4; ++nt) {
                const int colin = m16 + (nt << 4);
#pragma unroll
                for (int reg = 0; reg < 4; ++reg)
                    if (colin > rowin + reg) s[nt][reg] = -3.0e38f;
            }
        }

#pragma unroll
        for (int reg = 0; reg < 4; ++reg) {
            float mx = fmaxf(fmaxf(s[0][reg], s[1][reg]), fmaxf(s[2][reg], s[3][reg]));
            mx = fmaxf(mx, __shfl_xor(mx, 1));
            mx = fmaxf(mx, __shfl_xor(mx, 2));
            mx = fmaxf(mx, __shfl_xor(mx, 4));
            mx = fmaxf(mx, __shfl_xor(mx, 8));
            const float mnew  = fmaxf(m_i[reg], mx);
            const float alpha = __expf(m_i[reg] - mnew);
            m_i[reg] = mnew;
            float psum = 0.f;
            u16* lp = ldsW + ((quad << 2) + reg) * 72 + m16;
#pragma unroll
            for (int nt = 0; nt < 4; ++nt) {
                const float p = __expf(s[nt][reg] - mnew);
                psum += p;
                lp[nt << 4] = f2bf_rne(p);
                acc_o[nt][reg] *= alpha;
            }
            l_i[reg] = alpha * l_i[reg] + psum;
        }

        const bf16x8 p0 = *(const bf16x8*)(ldsW + m16 * 72 + (quad << 3));
        const bf16x8 p1 = *(const bf16x8*)(ldsW + m16 * 72 + 32 + (quad << 3));
        const u16* vb = Vt + (size_t)((b << 6) + m16) * SEQ + (jt << 6) + (quad << 3);
#pragma unroll
        for (int nt = 0; nt < 4; ++nt) {
            bf16x8 v0 = *(const bf16x8*)(vb + nt * 16 * SEQ);
            bf16x8 v1 = *(const bf16x8*)(vb + nt * 16 * SEQ + 32);
            acc_o[nt] = __builtin_amdgcn_mfma_f32_16x16x32_bf16(p0, v0, acc_o[nt], 0, 0, 0);
            acc_o[nt] = __builtin_amdgcn_mfma_f32_16x16x32_bf16(p1, v1, acc_o[nt], 0, 0, 0);
        }
    }

    // epilogue: write unnormalized partials
    u16* ob = Opart + (size_t)pid * 4096;
#pragma unroll
    for (int reg = 0; reg < 4; ++reg) {
        float l = l_i[reg];
        l += __shfl_xor(l, 1);
        l += __shfl_xor(l, 2);
        l += __shfl_xor(l, 4);
        l += __shfl_xor(l, 8);
        const int rowin = (wave << 4) + (quad << 2) + reg;
#pragma unroll
        for (int nt = 0; nt < 4; ++nt)
            ob[rowin * 64 + m16 + (nt << 4)] = f2bf_rne(acc_o[nt][reg]);
        if (m16 == 0) {
            Mp[pid * 64 + rowin] = m_i[reg];
            Lp[pid * 64 + rowin] = l;
        }
    }
}

// ---------------------------------------------------------------------------
// Kernel 3: combine the 4 chunk partials per (b, qtile) and normalize.
// Grid = 256 blocks (one per b,qt), 256 threads.
// ---------------------------------------------------------------------------
__global__ __launch_bounds__(256) void combine_kernel(
        const u16* __restrict__ Opart, const float* __restrict__ Mp,
        const float* __restrict__ Lp, float* __restrict__ out) {
    __shared__ float sm[4][64];
    __shared__ float sl[4][64];
    const int bq = blockIdx.x;         // b*64 + qt
    const int pidbase = bq << 2;
    const int t = threadIdx.x;
    {
        const int c = t >> 6, r = t & 63;
        sm[c][r] = Mp[(pidbase + c) * 64 + r];
        sl[c][r] = Lp[(pidbase + c) * 64 + r];
    }
    __syncthreads();

    const int col = t & 63;
    const int rg  = t >> 6;
#pragma unroll 4
    for (int i = 0; i < 16; ++i) {
        const int row = rg * 16 + i;
        float M = fmaxf(fmaxf(sm[0][row], sm[1][row]), fmaxf(sm[2][row], sm[3][row]));
        float num = 0.f, den = 0.f;
#pragma unroll
        for (int c = 0; c < 4; ++c) {
            const float w = __expf(sm[c][row] - M);
            den += w * sl[c][row];
            num += w * bf2f(Opart[(size_t)(pidbase + c) * 4096 + row * 64 + col]);
        }
        out[((size_t)bq << 12) + (row << 6) + col] = num / den;
    }
}

// ---------------------------------------------------------------------------
extern "C" void kernel_launch(void* const* d_in, const int* in_sizes, int n_in,
                              void* d_out, int out_size, void* d_ws, size_t ws_size,
                              hipStream_t stream) {
    const float* x  = (const float*)d_in[0];
    const float* Wq = (const float*)d_in[1];
    const float* Wk = (const float*)d_in[2];
    const float* Wv = (const float*)d_in[3];
    float* out = (float*)d_out;

    char* ws = (char*)d_ws;
    u16* Qw    = (u16*)(ws);                        // 2 MB
    u16* Kw    = (u16*)(ws + (2u << 20));           // 2 MB
    u16* Vt    = (u16*)(ws + (4u << 20));           // 2 MB
    u16* Wt    = (u16*)(ws + (6u << 20));           // 384 KB
    u16* Opart = (u16*)(ws + (13u << 19));          // 6.5 MB off, 8 MB
    float* Mp  = (float*)(ws + (29u << 19));        // 14.5 MB off, 256 KB
    float* Lp  = (float*)(ws + (59u << 18));        // 14.75 MB off, 256 KB

    wt_kernel<<<768, 256, 0, stream>>>(Wq, Wk, Wv, Wt);
    qkv_kernel<<<768, 256, 0, stream>>>(x, Wt, Qw, Kw, Vt);
    attn_part_kernel<<<1024, 256, 0, stream>>>(Qw, Kw, Vt, Opart, Mp, Lp);
    combine_kernel<<<256, 256, 0, stream>>>(Opart, Mp, Lp, out);
}

// Round 3
// 269.686 us; speedup vs baseline: 1.1973x; 1.1973x over previous
//
#include <hip/hip_runtime.h>
#include <hip/hip_bf16.h>
#include <stdint.h>

#define BATCH 4
#define SEQ   4096
#define EMB   1024
#define HD    64

typedef __bf16 bf16x8 __attribute__((ext_vector_type(8)));
typedef float  f32x4  __attribute__((ext_vector_type(4)));
typedef unsigned short u16;

union ABFrag { u16 s[8]; bf16x8 v; };

__device__ __forceinline__ u16 f2bf_rne(float f) {
    union { float f; uint32_t u; } cv; cv.f = f;
    uint32_t u = cv.u;
    return (u16)((u + 0x7fffu + ((u >> 16) & 1u)) >> 16);
}
__device__ __forceinline__ float bf2f(u16 h) {
    union { uint32_t u; float f; } cv; cv.u = ((uint32_t)h) << 16;
    return cv.f;
}
__device__ __forceinline__ void gload_lds16(const float* g, float* l) {
    __builtin_amdgcn_global_load_lds(
        (const __attribute__((address_space(1))) void*)g,
        (__attribute__((address_space(3))) void*)l, 16, 0, 0);
}

// ---------------------------------------------------------------------------
// Kernel 0: W (1024,64) fp32 x3 -> Wt bf16 [3][64][1024]  (transposed)
// ---------------------------------------------------------------------------
__global__ __launch_bounds__(256) void wt_kernel(
        const float* __restrict__ Wq, const float* __restrict__ Wk,
        const float* __restrict__ Wv, u16* __restrict__ Wt) {
    int idx = blockIdx.x * 256 + threadIdx.x;
    int i = idx >> 16;
    int r = idx & 65535;
    int n = r >> 10;
    int k = r & 1023;
    const float* W = (i == 0) ? Wq : (i == 1) ? Wk : Wv;
    Wt[idx] = f2bf_rne(W[k * HD + n]);
}

// ---------------------------------------------------------------------------
// Kernel 1: QKV projection, m97-style. 256 blocks x 64 rows. x tiles staged
// to LDS via async global_load_lds (16B), double-buffered, XOR-swizzled so
// A-frag ds_read_b128 is conflict-free. All 3 weights per block (x read 1x).
// ---------------------------------------------------------------------------
__global__ __launch_bounds__(256) void qkv_kernel(
        const float* __restrict__ x, const u16* __restrict__ Wt,
        u16* __restrict__ Qw, u16* __restrict__ Kw, u16* __restrict__ Vt) {
    __shared__ float xs[2][64 * 64];   // 2 x 16 KB

    const int t    = threadIdx.x;
    const int wave = t >> 6;
    const int lane = t & 63;
    const int m16  = lane & 15;
    const int quad = lane >> 4;
    const int R0   = blockIdx.x * 64;

    // DMA one 64x64-float tile (k-offset kt*64) into buffer buf.
    // LDS slot n (16B chunks) holds global (row n>>4, chunk (n&15)^(row&15)).
    #define ISSUE(buf_, kt_) do {                                              \
        const float* gb_ = x + (size_t)R0 * EMB + (kt_) * 64;                  \
        _Pragma("unroll")                                                      \
        for (int i2 = 0; i2 < 4; ++i2) {                                       \
            int rr_ = i2 * 16 + wave * 4 + quad;                               \
            int kc_ = m16 ^ (wave * 4 + quad);                                 \
            gload_lds16(gb_ + (size_t)rr_ * EMB + kc_ * 4,                     \
                        &xs[buf_][(i2 * 256 + wave * 64) * 4]);                \
        }                                                                      \
    } while (0)

    f32x4 acc[12];
#pragma unroll
    for (int a = 0; a < 12; ++a) acc[a] = (f32x4){0.f, 0.f, 0.f, 0.f};

    const int r_l = wave * 16 + m16;     // this lane's x row within tile
    ISSUE(0, 0);

    for (int kt = 0; kt < 16; ++kt) {
        const int buf = kt & 1;
        __syncthreads();                  // waits DMA of buf, guards buf^1 reuse
        if (kt < 15) ISSUE(buf ^ 1, kt + 1);

#pragma unroll
        for (int ks2 = 0; ks2 < 2; ++ks2) {
            const int kc0 = ks2 * 8 + quad * 2;
            const float4 a0 = *(const float4*)&xs[buf][(r_l * 16 + (kc0 ^ m16)) * 4];
            const float4 a1 = *(const float4*)&xs[buf][(r_l * 16 + ((kc0 + 1) ^ m16)) * 4];
            ABFrag af;
            af.s[0] = f2bf_rne(a0.x); af.s[1] = f2bf_rne(a0.y);
            af.s[2] = f2bf_rne(a0.z); af.s[3] = f2bf_rne(a0.w);
            af.s[4] = f2bf_rne(a1.x); af.s[5] = f2bf_rne(a1.y);
            af.s[6] = f2bf_rne(a1.z); af.s[7] = f2bf_rne(a1.w);
            const u16* wb = Wt + ((size_t)m16 << 10) + kt * 64 + ks2 * 32 + quad * 8;
#pragma unroll
            for (int w3 = 0; w3 < 3; ++w3) {
#pragma unroll
                for (int nt = 0; nt < 4; ++nt) {
                    bf16x8 bf = *(const bf16x8*)(wb + (w3 << 16) + (nt << 14));
                    acc[w3 * 4 + nt] = __builtin_amdgcn_mfma_f32_16x16x32_bf16(
                            af.v, bf, acc[w3 * 4 + nt], 0, 0, 0);
                }
            }
        }
    }
    #undef ISSUE

    // C layout: lane holds rows quad*4+reg, col = m16 + 16*nt
    const int rowbase = R0 + wave * 16 + (quad << 2);
    const int bidx = rowbase >> 12;
    const int t0   = rowbase & 4095;
#pragma unroll
    for (int nt = 0; nt < 4; ++nt) {
        const int col = m16 + (nt << 4);
#pragma unroll
        for (int reg = 0; reg < 4; ++reg) {
            Qw[(size_t)(rowbase + reg) * HD + col] = f2bf_rne(acc[nt][reg] * 0.03125f);
            Kw[(size_t)(rowbase + reg) * HD + col] = f2bf_rne(acc[4 + nt][reg]);
        }
        ushort4 vv;
        vv.x = f2bf_rne(acc[8 + nt][0]); vv.y = f2bf_rne(acc[8 + nt][1]);
        vv.z = f2bf_rne(acc[8 + nt][2]); vv.w = f2bf_rne(acc[8 + nt][3]);
        *(ushort4*)(Vt + (size_t)((bidx << 6) + col) * SEQ + t0) = vv;
    }
}

// ---------------------------------------------------------------------------
// Kernel 2: split-K causal flash attention, S^T formulation.
// Each lane owns ONE q-row (col of S^T): row-max = in-lane max + 2 shuffles,
// l/alpha are lane-scalars, O^T accumulates in C-layout.
// Grid 1024: r = pid>>8, i = pid&255, b = i&3, h = i>>2, qt = h ^ {0,63,32,31}[r],
// c = r; chunk processes jt = c, c+4, ... <= qt (per-CU-class work == const).
// ---------------------------------------------------------------------------
__global__ __launch_bounds__(256) void attn_part_kernel(
        const u16* __restrict__ Qw, const u16* __restrict__ Kw,
        const u16* __restrict__ Vt, u16* __restrict__ Opart,
        float* __restrict__ Mp, float* __restrict__ Lp) {
    __shared__ u16 ldsP[4][16 * 72];   // per-wave P[q][k], row stride 72 u16

    const int pid = blockIdx.x;
    const int r   = pid >> 8;
    const int i   = pid & 255;
    const int b   = i & 3;
    const int h   = i >> 2;
    const int qt  = h ^ (int)((0x1f203f00u >> (r * 8)) & 63u);  // {0,63,32,31}[r]
    const int c   = r;
    const int p_out = (((b << 6) + qt) << 2) + c;

    const int wave = threadIdx.x >> 6;
    const int lane = threadIdx.x & 63;
    const int m16  = lane & 15;
    const int quad = lane >> 4;

    // Q fragment as B-operand: n = m16 = q-row, k = quad*8+j
    const int qrow = (qt << 6) + (wave << 4) + m16;
    const u16* qbase = Qw + ((size_t)(b * SEQ + qrow) << 6);
    const bf16x8 qf0 = *(const bf16x8*)(qbase + (quad << 3));
    const bf16x8 qf1 = *(const bf16x8*)(qbase + 32 + (quad << 3));

    f32x4 acc[4];     // O^T: lane q = m16, d = dt*16 + quad*4 + reg
#pragma unroll
    for (int dt = 0; dt < 4; ++dt) acc[dt] = (f32x4){0.f, 0.f, 0.f, 0.f};
    float m_i = -3.0e38f;
    float l_i = 0.f;    // lane-partial (this quad's 16 k-positions)

    u16* ldsW = &ldsP[wave][0];

    for (int jt = c; jt <= qt; jt += 4) {
        // ---- S^T = K @ Q^T : A = K (m = k-pos), B = Q (n = q-row) ----
        const u16* kb = Kw + ((size_t)(b * SEQ + (jt << 6)) << 6);
        f32x4 s[4];
#pragma unroll
        for (int mt = 0; mt < 4; ++mt) {
            const u16* kr = kb + (((mt << 4) + m16) << 6) + (quad << 3);
            bf16x8 k0 = *(const bf16x8*)(kr);
            bf16x8 k1 = *(const bf16x8*)(kr + 32);
            s[mt] = (f32x4){0.f, 0.f, 0.f, 0.f};
            s[mt] = __builtin_amdgcn_mfma_f32_16x16x32_bf16(k0, qf0, s[mt], 0, 0, 0);
            s[mt] = __builtin_amdgcn_mfma_f32_16x16x32_bf16(k1, qf1, s[mt], 0, 0, 0);
        }

        if (jt == qt) {   // diagonal tile: mask k_in > q_in
            const int q_in = (wave << 4) + m16;
#pragma unroll
            for (int mt = 0; mt < 4; ++mt) {
                const int k_in = (mt << 4) + (quad << 2);
#pragma unroll
                for (int reg = 0; reg < 4; ++reg)
                    if (k_in + reg > q_in) s[mt][reg] = -3.0e38f;
            }
        }

        // ---- online softmax: in-lane max of 16, then 2 cross-quad hops ----
        float tm = fmaxf(fmaxf(s[0][0], s[0][1]), fmaxf(s[0][2], s[0][3]));
#pragma unroll
        for (int mt = 1; mt < 4; ++mt)
            tm = fmaxf(tm, fmaxf(fmaxf(s[mt][0], s[mt][1]), fmaxf(s[mt][2], s[mt][3])));
        tm = fmaxf(tm, __shfl_xor(tm, 16));
        tm = fmaxf(tm, __shfl_xor(tm, 32));

        const float mnew  = fmaxf(m_i, tm);
        const float alpha = __expf(m_i - mnew);
        m_i = mnew;

        float psum = 0.f;
#pragma unroll
        for (int mt = 0; mt < 4; ++mt) {
            const float p0 = __expf(s[mt][0] - mnew);
            const float p1 = __expf(s[mt][1] - mnew);
            const float p2 = __expf(s[mt][2] - mnew);
            const float p3 = __expf(s[mt][3] - mnew);
            psum += (p0 + p1) + (p2 + p3);
            ushort4 pv;
            pv.x = f2bf_rne(p0); pv.y = f2bf_rne(p1);
            pv.z = f2bf_rne(p2); pv.w = f2bf_rne(p3);
            // P[q = m16][k = mt*16 + quad*4 + reg]
            *(ushort4*)(ldsW + m16 * 72 + (mt << 4) + (quad << 2)) = pv;
        }
        l_i = l_i * alpha + psum;
#pragma unroll
        for (int dt = 0; dt < 4; ++dt)
#pragma unroll
            for (int reg = 0; reg < 4; ++reg) acc[dt][reg] *= alpha;

        // ---- O^T += V^T @ P^T : A = V^T (m = d), B = P (n = q) ----
        const bf16x8 p0 = *(const bf16x8*)(ldsW + m16 * 72 + (quad << 3));
        const bf16x8 p1 = *(const bf16x8*)(ldsW + m16 * 72 + 32 + (quad << 3));
        const u16* vb = Vt + ((size_t)(b << 6) + m16) * SEQ + (jt << 6) + (quad << 3);
#pragma unroll
        for (int dt = 0; dt < 4; ++dt) {
            bf16x8 v0 = *(const bf16x8*)(vb + (size_t)(dt << 4) * SEQ);
            bf16x8 v1 = *(const bf16x8*)(vb + (size_t)(dt << 4) * SEQ + 32);
            acc[dt] = __builtin_amdgcn_mfma_f32_16x16x32_bf16(v0, p0, acc[dt], 0, 0, 0);
            acc[dt] = __builtin_amdgcn_mfma_f32_16x16x32_bf16(v1, p1, acc[dt], 0, 0, 0);
        }
    }

    // ---- epilogue: reduce lane-partial l across quads, write partials ----
    float l = l_i;
    l += __shfl_xor(l, 16);
    l += __shfl_xor(l, 32);

    u16* ob = Opart + (size_t)p_out * 4096;
    const int qin = (wave << 4) + m16;
#pragma unroll
    for (int dt = 0; dt < 4; ++dt) {
        ushort4 vv;
        vv.x = f2bf_rne(acc[dt][0]); vv.y = f2bf_rne(acc[dt][1]);
        vv.z = f2bf_rne(acc[dt][2]); vv.w = f2bf_rne(acc[dt][3]);
        *(ushort4*)(ob + qin * 64 + (dt << 4) + (quad << 2)) = vv;
    }
    if (quad == 0) {
        Mp[p_out * 64 + qin] = m_i;
        Lp[p_out * 64 + qin] = l;
    }
}

// ---------------------------------------------------------------------------
// Kernel 3: combine the 4 chunk partials per (b, qtile) and normalize.
// ---------------------------------------------------------------------------
__global__ __launch_bounds__(256) void combine_kernel(
        const u16* __restrict__ Opart, const float* __restrict__ Mp,
        const float* __restrict__ Lp, float* __restrict__ out) {
    __shared__ float sm[4][64];
    __shared__ float sl[4][64];
    const int bq = blockIdx.x;
    const int pidbase = bq << 2;
    const int t = threadIdx.x;
    {
        const int c = t >> 6, r = t & 63;
        sm[c][r] = Mp[(pidbase + c) * 64 + r];
        sl[c][r] = Lp[(pidbase + c) * 64 + r];
    }
    __syncthreads();

    const int col = t & 63;
    const int rg  = t >> 6;
#pragma unroll 4
    for (int i = 0; i < 16; ++i) {
        const int row = rg * 16 + i;
        float M = fmaxf(fmaxf(sm[0][row], sm[1][row]), fmaxf(sm[2][row], sm[3][row]));
        float num = 0.f, den = 0.f;
#pragma unroll
        for (int c = 0; c < 4; ++c) {
            const float w = __expf(sm[c][row] - M);
            den += w * sl[c][row];
            num += w * bf2f(Opart[(size_t)(pidbase + c) * 4096 + row * 64 + col]);
        }
        out[((size_t)bq << 12) + (row << 6) + col] = num / den;
    }
}

// ---------------------------------------------------------------------------
extern "C" void kernel_launch(void* const* d_in, const int* in_sizes, int n_in,
                              void* d_out, int out_size, void* d_ws, size_t ws_size,
                              hipStream_t stream) {
    const float* x  = (const float*)d_in[0];
    const float* Wq = (const float*)d_in[1];
    const float* Wk = (const float*)d_in[2];
    const float* Wv = (const float*)d_in[3];
    float* out = (float*)d_out;

    char* ws = (char*)d_ws;
    u16* Qw    = (u16*)(ws);                        // 2 MB
    u16* Kw    = (u16*)(ws + (2u << 20));           // 2 MB
    u16* Vt    = (u16*)(ws + (4u << 20));           // 2 MB  [b][64][T]
    u16* Wt    = (u16*)(ws + (6u << 20));           // 384 KB
    u16* Opart = (u16*)(ws + (13u << 19));          // 8 MB
    float* Mp  = (float*)(ws + (29u << 19));        // 256 KB
    float* Lp  = (float*)(ws + (59u << 18));        // 256 KB

    wt_kernel<<<768, 256, 0, stream>>>(Wq, Wk, Wv, Wt);
    qkv_kernel<<<256, 256, 0, stream>>>(x, Wt, Qw, Kw, Vt);
    attn_part_kernel<<<1024, 256, 0, stream>>>(Qw, Kw, Vt, Opart, Mp, Lp);
    combine_kernel<<<256, 256, 0, stream>>>(Opart, Mp, Lp, out);
}

// Round 4
// 150.775 us; speedup vs baseline: 2.1415x; 1.7887x over previous
//
#include <hip/hip_runtime.h>
#include <hip/hip_bf16.h>
#include <stdint.h>

#define BATCH 4
#define SEQ   4096
#define EMB   1024
#define HD    64

typedef __bf16 bf16x8 __attribute__((ext_vector_type(8)));
typedef float  f32x4  __attribute__((ext_vector_type(4)));
typedef unsigned short u16;

union ABFrag { u16 s[8]; bf16x8 v; };

__device__ __forceinline__ u16 f2bf_rne(float f) {
    union { float f; uint32_t u; } cv; cv.f = f;
    uint32_t u = cv.u;
    return (u16)((u + 0x7fffu + ((u >> 16) & 1u)) >> 16);
}
__device__ __forceinline__ float bf2f(u16 h) {
    union { uint32_t u; float f; } cv; cv.u = ((uint32_t)h) << 16;
    return cv.f;
}
__device__ __forceinline__ void gld16(const void* g, void* l) {
    __builtin_amdgcn_global_load_lds(
        (const __attribute__((address_space(1))) void*)g,
        (__attribute__((address_space(3))) void*)l, 16, 0, 0);
}

// ---------------------------------------------------------------------------
// Kernel 0: W (1024,64) fp32 x3 -> Wt bf16 [3][64][1024]  (transposed)
// ---------------------------------------------------------------------------
__global__ __launch_bounds__(256) void wt_kernel(
        const float* __restrict__ Wq, const float* __restrict__ Wk,
        const float* __restrict__ Wv, u16* __restrict__ Wt) {
    int idx = blockIdx.x * 256 + threadIdx.x;
    int i = idx >> 16;
    int r = idx & 65535;
    int n = r >> 10;
    int k = r & 1023;
    const float* W = (i == 0) ? Wq : (i == 1) ? Wk : Wv;
    Wt[idx] = f2bf_rne(W[k * HD + n]);
}

// ---------------------------------------------------------------------------
// Kernel 1: QKV projection. 512 blocks, M=32 rows/block (2 blocks/CU).
// Both x (32x64 fp32) and Wt (192x64 bf16) tiles staged to LDS per kt via
// coalesced global_load_lds, double-buffered, XOR-chunk-swizzled.
// Wave (rh,ch): rh = row half (16 rows), ch = col half (6 of 12 MFMA tiles).
// ---------------------------------------------------------------------------
__global__ __launch_bounds__(256) void qkv_kernel(
        const float* __restrict__ x, const u16* __restrict__ Wt,
        u16* __restrict__ Qw, u16* __restrict__ Kw, u16* __restrict__ Vt) {
    __shared__ float xs[2][2048];     // 2 x 8 KB : 32 rows x 16 chunks(16B)
    __shared__ u16   wsb[2][12288];   // 2 x 24 KB: 192 rows x 8 chunks(16B)

    const int t    = threadIdx.x;
    const int wave = t >> 6;
    const int lane = t & 63;
    const int m16  = lane & 15;
    const int quad = lane >> 4;
    const int rh   = wave & 1;
    const int ch   = wave >> 1;
    const int R0   = blockIdx.x * 32;

    #define ISSUE(buf_, kt_) do {                                              \
        const int r4_ = lane >> 4, c16_ = lane & 15;                           \
        _Pragma("unroll")                                                      \
        for (int j_ = 0; j_ < 2; ++j_) {                                       \
            const int ii_  = wave + (j_ << 2);                                 \
            const int row_ = (ii_ << 2) + r4_;            /* 0..31 */          \
            const int kc_  = c16_ ^ (row_ & 15);                               \
            gld16(x + (size_t)(R0 + row_) * EMB + ((kt_) << 6) + (kc_ << 2),   \
                  &xs[buf_][ii_ << 8]);                                        \
        }                                                                      \
        const int r8_ = lane >> 3, c8_ = lane & 7;                             \
        _Pragma("unroll")                                                      \
        for (int j_ = 0; j_ < 6; ++j_) {                                       \
            const int rb_ = (wave * 6 + j_) << 3;         /* 0..184 */         \
            const int kw_ = c8_ ^ r8_;                                         \
            gld16(Wt + (size_t)(rb_ + r8_) * 1024 + ((kt_) << 6) + (kw_ << 3), \
                  &wsb[buf_][(wave * 6 + j_) << 9]);                           \
        }                                                                      \
    } while (0)

    f32x4 acc[6];
#pragma unroll
    for (int a = 0; a < 6; ++a) acc[a] = (f32x4){0.f, 0.f, 0.f, 0.f};

    const int row_x = rh * 16 + m16;
    ISSUE(0, 0);

    for (int kt = 0; kt < 16; ++kt) {
        const int buf = kt & 1;
        __syncthreads();
        if (kt < 15) ISSUE(buf ^ 1, kt + 1);

#pragma unroll
        for (int ks2 = 0; ks2 < 2; ++ks2) {
            const int c0 = (ks2 << 3) + (quad << 1);
            const float4 a0 = *(const float4*)&xs[buf][(row_x << 6) + ((c0 ^ m16) << 2)];
            const float4 a1 = *(const float4*)&xs[buf][(row_x << 6) + (((c0 + 1) ^ m16) << 2)];
            ABFrag af;
            af.s[0] = f2bf_rne(a0.x); af.s[1] = f2bf_rne(a0.y);
            af.s[2] = f2bf_rne(a0.z); af.s[3] = f2bf_rne(a0.w);
            af.s[4] = f2bf_rne(a1.x); af.s[5] = f2bf_rne(a1.y);
            af.s[6] = f2bf_rne(a1.z); af.s[7] = f2bf_rne(a1.w);
#pragma unroll
            for (int i = 0; i < 6; ++i) {
                const int tt   = ch * 6 + i;
                const int rowW = (tt << 4) + m16;          // 0..191
                const bf16x8 bf = *(const bf16x8*)&wsb[buf][
                        (rowW << 6) + ((((ks2 << 2) + quad) ^ (m16 & 7)) << 3)];
                acc[i] = __builtin_amdgcn_mfma_f32_16x16x32_bf16(af.v, bf, acc[i], 0, 0, 0);
            }
        }
    }
    #undef ISSUE

    // C layout: lane holds rows quad*4+reg, col = tt*16 + m16 (global col 0..191)
    const int rowbase = R0 + rh * 16 + (quad << 2);
    const int bidx = rowbase >> 12;
    const int t0   = rowbase & 4095;
#pragma unroll
    for (int i = 0; i < 6; ++i) {
        const int tt  = ch * 6 + i;
        const int w3  = tt >> 2;
        const int col = ((tt & 3) << 4) + m16;
        if (w3 == 0) {
#pragma unroll
            for (int reg = 0; reg < 4; ++reg)
                Qw[(size_t)(rowbase + reg) * HD + col] = f2bf_rne(acc[i][reg] * 0.03125f);
        } else if (w3 == 1) {
#pragma unroll
            for (int reg = 0; reg < 4; ++reg)
                Kw[(size_t)(rowbase + reg) * HD + col] = f2bf_rne(acc[i][reg]);
        } else {
            ushort4 vv;
            vv.x = f2bf_rne(acc[i][0]); vv.y = f2bf_rne(acc[i][1]);
            vv.z = f2bf_rne(acc[i][2]); vv.w = f2bf_rne(acc[i][3]);
            *(ushort4*)(Vt + (size_t)((bidx << 6) + col) * SEQ + t0) = vv;
        }
    }
}

// ---------------------------------------------------------------------------
// Kernel 2: split-K causal flash attention, S^T formulation, LDS-staged K/V.
// Per jt: K tile (64 kpos x 64 d) and V tile (64 d x 64 kpos) DMA'd into
// double-buffered LDS (XOR-chunk swizzle), shared by all 4 waves.
// Grid 1024 balanced: qt = h ^ {0,63,32,31}[r], chunk jt = r, r+4, ... <= qt.
// ---------------------------------------------------------------------------
__global__ __launch_bounds__(256) void attn_part_kernel(
        const u16* __restrict__ Qw, const u16* __restrict__ Kw,
        const u16* __restrict__ Vt, u16* __restrict__ Opart,
        float* __restrict__ Mp, float* __restrict__ Lp) {
    __shared__ u16 kv[2][2][4096];     // [buf][K/V][64 rows x 8 chunks] = 32 KB
    __shared__ u16 ldsP[4][16 * 72];   // per-wave P[q][k], row stride 72 u16

    const int pid = blockIdx.x;
    const int r   = pid >> 8;
    const int i   = pid & 255;
    const int b   = i & 3;
    const int h   = i >> 2;
    const int qt  = h ^ (int)((0x1f203f00u >> (r * 8)) & 63u);  // {0,63,32,31}[r]
    const int c   = r;
    const int p_out = (((b << 6) + qt) << 2) + c;

    const int wave = threadIdx.x >> 6;
    const int lane = threadIdx.x & 63;
    const int m16  = lane & 15;
    const int quad = lane >> 4;

    #define ISSUE_KV(buf_, jt_) do {                                           \
        const int r8_ = lane >> 3, c8_ = lane & 7;                             \
        const int kc_ = c8_ ^ r8_;                                             \
        _Pragma("unroll")                                                      \
        for (int j_ = 0; j_ < 2; ++j_) {                                       \
            const int row_ = ((wave * 2 + j_) << 3) + r8_;   /* 0..63 */       \
            gld16(Kw + ((size_t)(b * SEQ + ((jt_) << 6) + row_) << 6) + (kc_ << 3), \
                  &kv[buf_][0][(wave * 2 + j_) << 9]);                         \
            gld16(Vt + (size_t)((b << 6) + row_) * SEQ + ((jt_) << 6) + (kc_ << 3), \
                  &kv[buf_][1][(wave * 2 + j_) << 9]);                         \
        }                                                                      \
    } while (0)

    // Q fragment as B-operand: n = m16 = q-row, k = quad*8+j
    const int qrow = (qt << 6) + (wave << 4) + m16;
    const u16* qbase = Qw + ((size_t)(b * SEQ + qrow) << 6);
    const bf16x8 qf0 = *(const bf16x8*)(qbase + (quad << 3));
    const bf16x8 qf1 = *(const bf16x8*)(qbase + 32 + (quad << 3));

    f32x4 acc[4];     // O^T: lane q = m16, d = dt*16 + quad*4 + reg
#pragma unroll
    for (int dt = 0; dt < 4; ++dt) acc[dt] = (f32x4){0.f, 0.f, 0.f, 0.f};
    float m_i = -3.0e38f;
    float l_i = 0.f;

    u16* ldsW = &ldsP[wave][0];
    const int xs0 = (quad ^ (m16 & 7)) << 3;         // chunk slots for k-win 0
    const int xs1 = (((quad + 4)) ^ (m16 & 7)) << 3; // and k-win 1 (in u16)

    if (c <= qt) ISSUE_KV(0, c);

    int buf = 0;
    for (int jt = c; jt <= qt; jt += 4) {
        __syncthreads();                 // DMA of buf landed; buf^1 free
        if (jt + 4 <= qt) ISSUE_KV(buf ^ 1, jt + 4);

        // ---- S^T = K @ Q^T : A = K-frag from LDS ----
        f32x4 s[4];
#pragma unroll
        for (int mt = 0; mt < 4; ++mt) {
            const int base = ((mt << 4) + m16) << 6;
            bf16x8 k0 = *(const bf16x8*)&kv[buf][0][base + xs0];
            bf16x8 k1 = *(const bf16x8*)&kv[buf][0][base + xs1];
            s[mt] = (f32x4){0.f, 0.f, 0.f, 0.f};
            s[mt] = __builtin_amdgcn_mfma_f32_16x16x32_bf16(k0, qf0, s[mt], 0, 0, 0);
            s[mt] = __builtin_amdgcn_mfma_f32_16x16x32_bf16(k1, qf1, s[mt], 0, 0, 0);
        }

        if (jt == qt) {   // diagonal tile: mask k_in > q_in
            const int q_in = (wave << 4) + m16;
#pragma unroll
            for (int mt = 0; mt < 4; ++mt) {
                const int k_in = (mt << 4) + (quad << 2);
#pragma unroll
                for (int reg = 0; reg < 4; ++reg)
                    if (k_in + reg > q_in) s[mt][reg] = -3.0e38f;
            }
        }

        // ---- online softmax: lane owns one q-row; 2 cross-quad hops ----
        float tm = fmaxf(fmaxf(s[0][0], s[0][1]), fmaxf(s[0][2], s[0][3]));
#pragma unroll
        for (int mt = 1; mt < 4; ++mt)
            tm = fmaxf(tm, fmaxf(fmaxf(s[mt][0], s[mt][1]), fmaxf(s[mt][2], s[mt][3])));
        tm = fmaxf(tm, __shfl_xor(tm, 16));
        tm = fmaxf(tm, __shfl_xor(tm, 32));

        const float mnew  = fmaxf(m_i, tm);
        const float alpha = __expf(m_i - mnew);
        m_i = mnew;

        float psum = 0.f;
#pragma unroll
        for (int mt = 0; mt < 4; ++mt) {
            const float p0 = __expf(s[mt][0] - mnew);
            const float p1 = __expf(s[mt][1] - mnew);
            const float p2 = __expf(s[mt][2] - mnew);
            const float p3 = __expf(s[mt][3] - mnew);
            psum += (p0 + p1) + (p2 + p3);
            ushort4 pv;
            pv.x = f2bf_rne(p0); pv.y = f2bf_rne(p1);
            pv.z = f2bf_rne(p2); pv.w = f2bf_rne(p3);
            *(ushort4*)(ldsW + m16 * 72 + (mt << 4) + (quad << 2)) = pv;
        }
        l_i = l_i * alpha + psum;
#pragma unroll
        for (int dt = 0; dt < 4; ++dt)
#pragma unroll
            for (int reg = 0; reg < 4; ++reg) acc[dt][reg] *= alpha;

        // ---- O^T += V^T @ P^T : A = V-frag from LDS ----
        const bf16x8 p0 = *(const bf16x8*)(ldsW + m16 * 72 + (quad << 3));
        const bf16x8 p1 = *(const bf16x8*)(ldsW + m16 * 72 + 32 + (quad << 3));
#pragma unroll
        for (int dt = 0; dt < 4; ++dt) {
            const int base = ((dt << 4) + m16) << 6;
            bf16x8 v0 = *(const bf16x8*)&kv[buf][1][base + xs0];
            bf16x8 v1 = *(const bf16x8*)&kv[buf][1][base + xs1];
            acc[dt] = __builtin_amdgcn_mfma_f32_16x16x32_bf16(v0, p0, acc[dt], 0, 0, 0);
            acc[dt] = __builtin_amdgcn_mfma_f32_16x16x32_bf16(v1, p1, acc[dt], 0, 0, 0);
        }
        buf ^= 1;
    }
    #undef ISSUE_KV

    float l = l_i;
    l += __shfl_xor(l, 16);
    l += __shfl_xor(l, 32);

    u16* ob = Opart + (size_t)p_out * 4096;
    const int qin = (wave << 4) + m16;
#pragma unroll
    for (int dt = 0; dt < 4; ++dt) {
        ushort4 vv;
        vv.x = f2bf_rne(acc[dt][0]); vv.y = f2bf_rne(acc[dt][1]);
        vv.z = f2bf_rne(acc[dt][2]); vv.w = f2bf_rne(acc[dt][3]);
        *(ushort4*)(ob + qin * 64 + (dt << 4) + (quad << 2)) = vv;
    }
    if (quad == 0) {
        Mp[p_out * 64 + qin] = m_i;
        Lp[p_out * 64 + qin] = l;
    }
}

// ---------------------------------------------------------------------------
// Kernel 3: combine the 4 chunk partials per (b, qtile, rowquarter), normalize.
// Grid 1024, vectorized ushort4 reads / float4 writes.
// ---------------------------------------------------------------------------
__global__ __launch_bounds__(256) void combine_kernel(
        const u16* __restrict__ Opart, const float* __restrict__ Mp,
        const float* __restrict__ Lp, float* __restrict__ out) {
    __shared__ float sm[4][16];
    __shared__ float sl[4][16];
    const int bq = blockIdx.x >> 2;          // b*64 + qt
    const int rq = blockIdx.x & 3;           // row quarter
    const int pidbase = bq << 2;
    const int t = threadIdx.x;
    if (t < 64) {
        const int cc = t >> 4, rr = t & 15;
        sm[cc][rr] = Mp[(pidbase + cc) * 64 + rq * 16 + rr];
        sl[cc][rr] = Lp[(pidbase + cc) * 64 + rq * 16 + rr];
    }
    __syncthreads();

    const int row_l = t >> 4;                // 0..15
    const int c4    = (t & 15) << 2;         // col base
    const int row   = rq * 16 + row_l;

    const float M = fmaxf(fmaxf(sm[0][row_l], sm[1][row_l]),
                          fmaxf(sm[2][row_l], sm[3][row_l]));
    float n0 = 0.f, n1 = 0.f, n2 = 0.f, n3 = 0.f, den = 0.f;
#pragma unroll
    for (int cc = 0; cc < 4; ++cc) {
        const float w = __expf(sm[cc][row_l] - M);
        den += w * sl[cc][row_l];
        const ushort4 op = *(const ushort4*)&Opart[
                (size_t)(pidbase + cc) * 4096 + row * 64 + c4];
        n0 += w * bf2f(op.x); n1 += w * bf2f(op.y);
        n2 += w * bf2f(op.z); n3 += w * bf2f(op.w);
    }
    const float rd = 1.0f / den;
    float4 o; o.x = n0 * rd; o.y = n1 * rd; o.z = n2 * rd; o.w = n3 * rd;
    *(float4*)&out[((size_t)bq << 12) + (row << 6) + c4] = o;
}

// ---------------------------------------------------------------------------
extern "C" void kernel_launch(void* const* d_in, const int* in_sizes, int n_in,
                              void* d_out, int out_size, void* d_ws, size_t ws_size,
                              hipStream_t stream) {
    const float* x  = (const float*)d_in[0];
    const float* Wq = (const float*)d_in[1];
    const float* Wk = (const float*)d_in[2];
    const float* Wv = (const float*)d_in[3];
    float* out = (float*)d_out;

    char* ws = (char*)d_ws;
    u16* Qw    = (u16*)(ws);                        // 2 MB
    u16* Kw    = (u16*)(ws + (2u << 20));           // 2 MB
    u16* Vt    = (u16*)(ws + (4u << 20));           // 2 MB  [b][64][T]
    u16* Wt    = (u16*)(ws + (6u << 20));           // 384 KB
    u16* Opart = (u16*)(ws + (13u << 19));          // 8 MB
    float* Mp  = (float*)(ws + (29u << 19));        // 256 KB
    float* Lp  = (float*)(ws + (59u << 18));        // 256 KB

    wt_kernel<<<768, 256, 0, stream>>>(Wq, Wk, Wv, Wt);
    qkv_kernel<<<512, 256, 0, stream>>>(x, Wt, Qw, Kw, Vt);
    attn_part_kernel<<<1024, 256, 0, stream>>>(Qw, Kw, Vt, Opart, Mp, Lp);
    combine_kernel<<<1024, 256, 0, stream>>>(Opart, Mp, Lp, out);
}